// Round 3
// baseline (303161.743 us; speedup 1.0000x reference)
//
#include <hip/hip_runtime.h>
#include <math.h>

// Problem constants
#define HH   1028         // hidden size
#define TT   16384        // timesteps
#define HP   1088         // padded hidden for LDS staging (17*64)
#define HS   1056         // h row stride in floats: 4224 B = 33 cache lines (row-isolated)
#define NWG  257          // workgroups per recurrence kernel (4 units each: 257*4 = 1028)
#define NREP 8            // counter replicas
#define RSTRIDE 64        // ints between replicas (256 B)

// ---------- MALL-coherent access helpers ----------
__device__ __forceinline__ int ld_cnt(const int* p) {
    return __hip_atomic_load(p, __ATOMIC_RELAXED, __HIP_MEMORY_SCOPE_AGENT);
}
__device__ __forceinline__ void st_u64(unsigned long long* p, unsigned long long v) {
    __hip_atomic_store(p, v, __ATOMIC_RELAXED, __HIP_MEMORY_SCOPE_AGENT);
}
__device__ __forceinline__ void add_cnt(int* p) {
    (void)__hip_atomic_fetch_add(p, 1, __ATOMIC_RELAXED, __HIP_MEMORY_SCOPE_AGENT);
}
__device__ __forceinline__ float sigmf(float x) { return 1.0f / (1.0f + expf(-x)); }

// Full-wave poll: lane (tid%64)==0 loads one replica; wave exits when cnt >= tgt.
__device__ __forceinline__ void poll_cnt(const int* cnt, int rep, int tgt, long long& budget) {
    const bool ld = ((threadIdx.x & 63) == 0);
    const int* p = cnt + rep * RSTRIDE;
    for (;;) {
        int v = ld ? ld_cnt(p) : 0x7fffffff;
        if (__all(v >= tgt)) break;
        if (--budget < 0) break;                 // hang safety valve
        __builtin_amdgcn_s_sleep(3);
    }
    asm volatile("" ::: "memory");               // keep stage loads below the poll
}

// Publish: lane0 stores 4 h floats (16B, one line) + ack + 8 fire-forget adds.
__device__ __forceinline__ void publish4(float* dst, float4 o4, int* cnt) {
    float2 lo2 = make_float2(o4.x, o4.y);
    float2 hi2 = make_float2(o4.z, o4.w);
    unsigned long long lo, hi;
    __builtin_memcpy(&lo, &lo2, 8);
    __builtin_memcpy(&hi, &hi2, 8);
    st_u64((unsigned long long*)dst, lo);
    st_u64((unsigned long long*)dst + 1, hi);
    asm volatile("s_waitcnt vmcnt(0)" ::: "memory");   // all published data acked at MALL
#pragma unroll
    for (int r = 0; r < NREP; ++r) add_cnt(cnt + r * RSTRIDE);
}

// ---------- init: counters = 0 ----------
__global__ void wn_init(int* cntA, int* cntB) {
    const int i = threadIdx.x;
    if (i < NREP) {
        __hip_atomic_store(cntA + i * RSTRIDE, 0, __ATOMIC_RELAXED, __HIP_MEMORY_SCOPE_AGENT);
        __hip_atomic_store(cntB + i * RSTRIDE, 0, __ATOMIC_RELAXED, __HIP_MEMORY_SCOPE_AGENT);
    }
}

// ---------- layer 0 recurrence ----------
__global__ __launch_bounds__(256, 2) void lstm0_seq(
    const float* __restrict__ x,
    const float* __restrict__ w_ih0,   // [4H] (input size 1)
    const float* __restrict__ w_hh0,   // [4H][H]
    const float* __restrict__ b_ih0,
    const float* __restrict__ b_hh0,
    float* __restrict__ h1,            // [T][HS]
    int* __restrict__ cnt)
{
    __shared__ float h_lds[HP];
    __shared__ float gate_lds[16];

    const int tid  = threadIdx.x;
    const int wg   = blockIdx.x;        // 0..256
    const int rl   = tid >> 4;          // 0..15 : gate*4 + du
    const int k0   = tid & 15;
    const int gate = rl >> 2;
    const int du   = rl & 3;
    const int u    = wg * 4 + du;
    const int row  = gate * HH + u;
    const int myrep = (wg + (tid >> 6)) & 7;

    for (int i = tid; i < HP; i += 256) h_lds[i] = 0.0f;

    float wv[17][4];
#pragma unroll
    for (int m = 0; m < 17; ++m) {
        const int j = k0 * 4 + m * 64;
#pragma unroll
        for (int q = 0; q < 4; ++q)
            wv[m][q] = (j + q < HH) ? w_hh0[(size_t)row * HH + j + q] : 0.0f;
    }
#pragma unroll
    for (int m = 0; m < 17; ++m)
#pragma unroll
        for (int q = 0; q < 4; ++q)
            asm volatile("" : "+v"(wv[m][q]));

    const float wx = w_ih0[row];
    const float bs = b_ih0[row] + b_hh0[row];

    long long budget = 100000000LL;
    int tgt = NWG;
    float c_reg = 0.0f;
    for (int t = 0; t < TT; ++t) {
        const float xt = x[t];
        if (t > 0) {
            poll_cnt(cnt, myrep, tgt - NWG, budget);   // wait step t-1 complete (cnt >= NWG*t)
            const float* hp = h1 + (size_t)(t - 1) * HS;
            *(float4*)&h_lds[tid * 4] = *(const float4*)(hp + tid * 4);
            if (tid == 0) *(float4*)&h_lds[1024] = *(const float4*)(hp + 1024);
        }
        __syncthreads();                               // SYNC_B: stage visible to all
        float acc = 0.0f;
#pragma unroll
        for (int m = 0; m < 17; ++m) {
            const float4 hv = *(const float4*)&h_lds[k0 * 4 + m * 64];
            acc = fmaf(wv[m][0], hv.x, acc);
            acc = fmaf(wv[m][1], hv.y, acc);
            acc = fmaf(wv[m][2], hv.z, acc);
            acc = fmaf(wv[m][3], hv.w, acc);
        }
#pragma unroll
        for (int off = 1; off < 16; off <<= 1) acc += __shfl_xor(acc, off);
        if (k0 == 0) gate_lds[rl] = acc + xt * wx + bs;
        __syncthreads();                               // SYNC_C: gates visible; FMA reads done
        if (tid < 64) {                                // wave0 epilogue
            float hv = 0.0f;
            if (tid < 4) {
                const float gi = gate_lds[tid];
                const float gf = gate_lds[4 + tid];
                const float gg = gate_lds[8 + tid];
                const float go = gate_lds[12 + tid];
                const float iv = sigmf(gi), fv = sigmf(gf), gv = tanhf(gg), ov = sigmf(go);
                c_reg = fv * c_reg + iv * gv;
                hv = ov * tanhf(c_reg);
            }
            float4 o4;
            o4.x = __shfl(hv, 0); o4.y = __shfl(hv, 1);
            o4.z = __shfl(hv, 2); o4.w = __shfl(hv, 3);
            if (tid == 0) publish4(h1 + (size_t)t * HS + wg * 4, o4, cnt);
        }
        tgt += NWG;
    }
}

// ---------- layer 1 recurrence (fused w_ih1 GEMV, consumes finished h1) ----------
__global__ __launch_bounds__(256, 2) void lstm1_seq(
    const float* __restrict__ h1,      // [T][HS] (finished, stable)
    const float* __restrict__ w_ih1,   // [4H][H]
    const float* __restrict__ w_hh1,   // [4H][H]
    const float* __restrict__ b_ih1,
    const float* __restrict__ b_hh1,
    float* __restrict__ h2,            // [T][HS]
    int* __restrict__ cnt)
{
    __shared__ float a_lds[HP];   // h1[t]
    __shared__ float b_lds[HP];   // h2[t-1]
    __shared__ float gate_lds[16];

    const int tid  = threadIdx.x;
    const int wg   = blockIdx.x;
    const int rl   = tid >> 4;
    const int k0   = tid & 15;
    const int gate = rl >> 2;
    const int du   = rl & 3;
    const int u    = wg * 4 + du;
    const int row  = gate * HH + u;
    const int myrep = (wg + (tid >> 6)) & 7;

    for (int i = tid; i < HP; i += 256) { a_lds[i] = 0.0f; b_lds[i] = 0.0f; }

    float wiv[17][4], whv[17][4];
#pragma unroll
    for (int m = 0; m < 17; ++m) {
        const int j = k0 * 4 + m * 64;
#pragma unroll
        for (int q = 0; q < 4; ++q) {
            const bool inb = (j + q < HH);
            wiv[m][q] = inb ? w_ih1[(size_t)row * HH + j + q] : 0.0f;
            whv[m][q] = inb ? w_hh1[(size_t)row * HH + j + q] : 0.0f;
        }
    }
#pragma unroll
    for (int m = 0; m < 17; ++m)
#pragma unroll
        for (int q = 0; q < 4; ++q) {
            asm volatile("" : "+v"(wiv[m][q]));
            asm volatile("" : "+v"(whv[m][q]));
        }
    const float bs = b_ih1[row] + b_hh1[row];

    long long budget = 100000000LL;
    int tgt = NWG;
    float c_reg = 0.0f;
    for (int t = 0; t < TT; ++t) {
        // prefetch h1[t] into regs (stable data; overlaps the poll)
        const float* ap = h1 + (size_t)t * HS;
        float4 av = *(const float4*)(ap + tid * 4);
        float4 av2 = make_float4(0.f, 0.f, 0.f, 0.f);
        if (tid == 0) av2 = *(const float4*)(ap + 1024);
        if (t > 0) {
            poll_cnt(cnt, myrep, tgt - NWG, budget);
            const float* bp = h2 + (size_t)(t - 1) * HS;
            *(float4*)&b_lds[tid * 4] = *(const float4*)(bp + tid * 4);
            if (tid == 0) *(float4*)&b_lds[1024] = *(const float4*)(bp + 1024);
        }
        *(float4*)&a_lds[tid * 4] = av;
        if (tid == 0) *(float4*)&a_lds[1024] = av2;
        __syncthreads();                               // SYNC_B

        float acc = 0.0f;
#pragma unroll
        for (int m = 0; m < 17; ++m) {
            const float4 ha = *(const float4*)&a_lds[k0 * 4 + m * 64];
            const float4 hb = *(const float4*)&b_lds[k0 * 4 + m * 64];
            acc = fmaf(wiv[m][0], ha.x, acc);
            acc = fmaf(wiv[m][1], ha.y, acc);
            acc = fmaf(wiv[m][2], ha.z, acc);
            acc = fmaf(wiv[m][3], ha.w, acc);
            acc = fmaf(whv[m][0], hb.x, acc);
            acc = fmaf(whv[m][1], hb.y, acc);
            acc = fmaf(whv[m][2], hb.z, acc);
            acc = fmaf(whv[m][3], hb.w, acc);
        }
#pragma unroll
        for (int off = 1; off < 16; off <<= 1) acc += __shfl_xor(acc, off);
        if (k0 == 0) gate_lds[rl] = acc + bs;
        __syncthreads();                               // SYNC_C
        if (tid < 64) {
            float hv = 0.0f;
            if (tid < 4) {
                const float gi = gate_lds[tid];
                const float gf = gate_lds[4 + tid];
                const float gg = gate_lds[8 + tid];
                const float go = gate_lds[12 + tid];
                const float iv = sigmf(gi), fv = sigmf(gf), gv = tanhf(gg), ov = sigmf(go);
                c_reg = fv * c_reg + iv * gv;
                hv = ov * tanhf(c_reg);
            }
            float4 o4;
            o4.x = __shfl(hv, 0); o4.y = __shfl(hv, 1);
            o4.z = __shfl(hv, 2); o4.w = __shfl(hv, 3);
            if (tid == 0) publish4(h2 + (size_t)t * HS + wg * 4, o4, cnt);
        }
        tgt += NWG;
    }
}

// ---------- final projection: out[t] = lin_w . h2[t] + lin_b ----------
__global__ __launch_bounds__(256) void wn_proj(
    const float* __restrict__ h2,
    const float* __restrict__ lin_w,
    const float* __restrict__ lin_b,
    float* __restrict__ out)
{
    const int lane = threadIdx.x & 63;
    const int wv   = threadIdx.x >> 6;
    const int t    = blockIdx.x * 4 + wv;
    const float* hp = h2 + (size_t)t * HS;
    float acc = 0.0f;
#pragma unroll
    for (int m = 0; m < 4; ++m) {
        const int j = lane * 4 + m * 256;        // covers [0,1024)
        const float4 h4 = *(const float4*)(hp + j);
        const float4 w4 = *(const float4*)(lin_w + j);
        acc += h4.x * w4.x + h4.y * w4.y + h4.z * w4.z + h4.w * w4.w;
    }
    if (lane == 0) {
#pragma unroll
        for (int j = 1024; j < HH; ++j) acc += hp[j] * lin_w[j];
    }
#pragma unroll
    for (int off = 1; off < 64; off <<= 1) acc += __shfl_xor(acc, off);
    if (lane == 0) out[t] = acc + lin_b[0];
}

extern "C" void kernel_launch(void* const* d_in, const int* in_sizes, int n_in,
                              void* d_out, int out_size, void* d_ws, size_t ws_size,
                              hipStream_t stream) {
    const float* x     = (const float*)d_in[0];
    const float* w_ih0 = (const float*)d_in[1];
    const float* w_hh0 = (const float*)d_in[2];
    const float* b_ih0 = (const float*)d_in[3];
    const float* b_hh0 = (const float*)d_in[4];
    const float* w_ih1 = (const float*)d_in[5];
    const float* w_hh1 = (const float*)d_in[6];
    const float* b_ih1 = (const float*)d_in[7];
    const float* b_hh1 = (const float*)d_in[8];
    const float* lin_w = (const float*)d_in[9];
    const float* lin_b = (const float*)d_in[10];
    float* out = (float*)d_out;

    char* ws = (char*)d_ws;
    const size_t SZ = (size_t)TT * HS * sizeof(float);   // 69,206,016 B per h-buffer
    float* h1 = (float*)(ws);
    float* h2 = (float*)(ws + SZ);
    int* cntA = (int*)(ws + 2 * SZ);                     // 8 replicas * 256 B
    int* cntB = (int*)(ws + 2 * SZ + NREP * RSTRIDE * sizeof(int));

    wn_init<<<1, 64, 0, stream>>>(cntA, cntB);
    lstm0_seq<<<NWG, 256, 0, stream>>>(x, w_ih0, w_hh0, b_ih0, b_hh0, h1, cntA);
    lstm1_seq<<<NWG, 256, 0, stream>>>(h1, w_ih1, w_hh1, b_ih1, b_hh1, h2, cntB);
    wn_proj<<<TT / 4, 256, 0, stream>>>(h2, lin_w, lin_b, out);
}

// Round 5
// 106785.596 us; speedup vs baseline: 2.8390x; 2.8390x over previous
//
#include <hip/hip_runtime.h>
#include <math.h>

// Problem constants
#define HH    1028        // real hidden size
#define TT    16384       // timesteps
#define UP    1056        // padded units / padded K (= 16*66 = 8*132)
#define HS    1056        // h row stride in floats (4224 B = 66 lines, 64B-aligned)
#define NWG0  66          // layer-0 WGs, 16 units each
#define NWG1  132         // layer-1 WGs, 8 units each
#define NWGT  (NWG0 + NWG1)
#define NF64  17          // u64 words per flag array (17*4 = 68 >= 66; 132 needs 33 shorts.. see below)

// Flag arrays: ushort step counters (completed-step count, 0..16384 — never wraps).
// f0: 66 used, padded to 136 with 0xffff. f1: 132 used, padded to 136 with 0xffff.
// Poll reads 34 u64 (both arrays same shape: 136 ushorts = 17 u64).

// ---------- MALL-coherent primitives (no atomics-RMW, no cache-walk ops) ----------
__device__ __forceinline__ void st_u64(unsigned long long* p, unsigned long long v) {
    __hip_atomic_store(p, v, __ATOMIC_RELAXED, __HIP_MEMORY_SCOPE_AGENT);
}
__device__ __forceinline__ void st_u16(unsigned short* p, unsigned short v) {
    __hip_atomic_store(p, v, __ATOMIC_RELAXED, __HIP_MEMORY_SCOPE_AGENT);
}
__device__ __forceinline__ float sigmf(float x) { return 1.0f / (1.0f + expf(-x)); }

// One-wave poll: lanes 0..16 each load one u64 (4 ushort counters); wave exits
// when every counter >= tgt. Monotone comparison — robust to any peer skew.
__device__ __forceinline__ void poll_ge(const unsigned long long* f, unsigned tgt, long long& budget) {
    const int lane = threadIdx.x & 63;
    const bool act = lane < NF64;
    const unsigned long long* p = f + (act ? lane : 0);
    for (;;) {
        bool ok = true;
        if (act) {
            unsigned long long v = __hip_atomic_load(p, __ATOMIC_RELAXED, __HIP_MEMORY_SCOPE_AGENT);
            unsigned a0 = (unsigned)(v & 0xffffu);
            unsigned a1 = (unsigned)((v >> 16) & 0xffffu);
            unsigned a2 = (unsigned)((v >> 32) & 0xffffu);
            unsigned a3 = (unsigned)((v >> 48) & 0xffffu);
            ok = (a0 >= tgt) & (a1 >= tgt) & (a2 >= tgt) & (a3 >= tgt);
        }
        if (__all(ok)) break;
        if (--budget < 0) break;              // hang safety valve
        __builtin_amdgcn_s_sleep(2);
    }
    asm volatile("" ::: "memory");            // keep data loads below the poll
}

// ---------- init: counters = 0 (0 steps done), pad entries = 0xffff ----------
__global__ void wn_init(unsigned short* f0, unsigned short* f1) {
    const int i = threadIdx.x;
    if (i < 136) {
        st_u16(f0 + i, (i < NWG0) ? (unsigned short)0 : (unsigned short)0xffff);
        st_u16(f1 + i, (i < NWG1) ? (unsigned short)0 : (unsigned short)0xffff);
    }
}

// ---------- fused 2-layer LSTM recurrence ----------
__global__ __launch_bounds__(1024, 4) void wn_fused(
    const float* __restrict__ x,
    const float* __restrict__ w_ih0, const float* __restrict__ w_hh0,
    const float* __restrict__ b_ih0, const float* __restrict__ b_hh0,
    const float* __restrict__ w_ih1, const float* __restrict__ w_hh1,
    const float* __restrict__ b_ih1, const float* __restrict__ b_hh1,
    float* __restrict__ h1, float* __restrict__ h2,
    unsigned long long* __restrict__ f0, unsigned long long* __restrict__ f1)
{
    __shared__ float smem[2 * UP + 64];      // L0: h | gates; L1: a | b | gates
    const int tid  = threadIdx.x;
    const int lane = tid & 63;

    if (blockIdx.x < NWG0) {
        // ================= layer 0 : 16 units, 64 rows x 16 lanes =================
        float* h_lds    = smem;
        float* gate_lds = smem + 2 * UP;
        const int wg   = blockIdx.x;
        const int row  = tid >> 4;           // 0..63 = gate*16 + du
        const int k0   = tid & 15;
        const int gate = row >> 4;
        const int du   = row & 15;
        const int u    = wg * 16 + du;
        const bool real = (u < HH);
        const int wrow = gate * HH + (real ? u : 0);

        for (int i = tid; i < UP; i += 1024) h_lds[i] = 0.0f;

        float wv[16][4], wt0 = 0.f, wt1 = 0.f;
#pragma unroll
        for (int m = 0; m < 16; ++m) {
            const int j = k0 * 4 + m * 64;
#pragma unroll
            for (int q = 0; q < 4; ++q)
                wv[m][q] = (real && j + q < HH) ? w_hh0[(size_t)wrow * HH + j + q] : 0.0f;
        }
        {   const int j = 1024 + k0 * 2;
            wt0 = (real && j     < HH) ? w_hh0[(size_t)wrow * HH + j]     : 0.0f;
            wt1 = (real && j + 1 < HH) ? w_hh0[(size_t)wrow * HH + j + 1] : 0.0f; }
#pragma unroll
        for (int m = 0; m < 16; ++m)
#pragma unroll
            for (int q = 0; q < 4; ++q) asm volatile("" : "+v"(wv[m][q]));
        asm volatile("" : "+v"(wt0), "+v"(wt1));

        const float wx = real ? w_ih0[wrow] : 0.0f;
        const float bs = real ? (b_ih0[wrow] + b_hh0[wrow]) : 0.0f;

        long long budget = 100000000LL;
        float c_reg = 0.0f;
        for (int t = 0; t < TT; ++t) {
            const float xt = x[t];
            if (t > 0 && tid < 64) {         // wave0: poll peers done step t-1, stage h1[t-1]
                poll_ge(f0, (unsigned)t, budget);
                const float* hp = h1 + (size_t)(t - 1) * HS;
                float4 v0 = *(const float4*)(hp + lane * 4 + 0);
                float4 v1 = *(const float4*)(hp + lane * 4 + 256);
                float4 v2 = *(const float4*)(hp + lane * 4 + 512);
                float4 v3 = *(const float4*)(hp + lane * 4 + 768);
                float  vt = (lane < 32) ? hp[1024 + lane] : 0.0f;
                *(float4*)&h_lds[lane * 4 + 0]   = v0;
                *(float4*)&h_lds[lane * 4 + 256] = v1;
                *(float4*)&h_lds[lane * 4 + 512] = v2;
                *(float4*)&h_lds[lane * 4 + 768] = v3;
                if (lane < 32) h_lds[1024 + lane] = vt;
            }
            __syncthreads();                 // stage visible
            float acc = 0.0f;
#pragma unroll
            for (int m = 0; m < 16; ++m) {
                const float4 hv = *(const float4*)&h_lds[k0 * 4 + m * 64];
                acc = fmaf(wv[m][0], hv.x, acc);
                acc = fmaf(wv[m][1], hv.y, acc);
                acc = fmaf(wv[m][2], hv.z, acc);
                acc = fmaf(wv[m][3], hv.w, acc);
            }
            {   const float2 hv = *(const float2*)&h_lds[1024 + k0 * 2];
                acc = fmaf(wt0, hv.x, acc);
                acc = fmaf(wt1, hv.y, acc); }
#pragma unroll
            for (int off = 1; off < 16; off <<= 1) acc += __shfl_xor(acc, off);
            if (k0 == 0) gate_lds[row] = acc + xt * wx + bs;
            __syncthreads();                 // gates visible; LDS reads done
            if (tid < 64) {                  // wave0 epilogue + publish
                float hv = 0.0f;
                if (tid < 16) {
                    const float gi = gate_lds[tid];
                    const float gf = gate_lds[16 + tid];
                    const float gg = gate_lds[32 + tid];
                    const float go = gate_lds[48 + tid];
                    const float iv = sigmf(gi), fv = sigmf(gf), gv = tanhf(gg), ov = sigmf(go);
                    c_reg = fv * c_reg + iv * gv;
                    hv = ov * tanhf(c_reg);
                }
                const float a = __shfl(hv, (lane & 7) * 2);
                const float b = __shfl(hv, (lane & 7) * 2 + 1);
                if (tid < 8) {
                    float2 f2 = make_float2(a, b);
                    unsigned long long pk;
                    __builtin_memcpy(&pk, &f2, 8);
                    st_u64((unsigned long long*)(h1 + (size_t)t * HS + wg * 16) + tid, pk);
                }
                asm volatile("s_waitcnt vmcnt(0)" ::: "memory");   // h acked at MALL
                if (tid == 0) st_u16((unsigned short*)f0 + wg, (unsigned short)(t + 1));
            }
        }
    } else {
        // ================= layer 1 : 8 units, 32 rows x 32 lanes =================
        float* a_lds    = smem;              // h1[t]
        float* b_lds    = smem + UP;         // h2[t-1]
        float* gate_lds = smem + 2 * UP;
        const int wg   = blockIdx.x - NWG0;  // 0..131
        const int row  = tid >> 5;           // 0..31 = gate*8 + du
        const int k0   = tid & 31;
        const int gate = row >> 3;
        const int du   = row & 7;
        const int u    = wg * 8 + du;
        const bool real = (u < HH);
        const int wrow = gate * HH + (real ? u : 0);

        for (int i = tid; i < 2 * UP; i += 1024) smem[i] = 0.0f;

        float wiv[8][4], whv[8][4], wit = 0.f, wht = 0.f;
#pragma unroll
        for (int m = 0; m < 8; ++m) {
            const int j = k0 * 4 + m * 128;
#pragma unroll
            for (int q = 0; q < 4; ++q) {
                const bool inb = real && (j + q < HH);
                wiv[m][q] = inb ? w_ih1[(size_t)wrow * HH + j + q] : 0.0f;
                whv[m][q] = inb ? w_hh1[(size_t)wrow * HH + j + q] : 0.0f;
            }
        }
        {   const int j = 1024 + k0;
            wit = (real && j < HH) ? w_ih1[(size_t)wrow * HH + j] : 0.0f;
            wht = (real && j < HH) ? w_hh1[(size_t)wrow * HH + j] : 0.0f; }
#pragma unroll
        for (int m = 0; m < 8; ++m)
#pragma unroll
            for (int q = 0; q < 4; ++q) {
                asm volatile("" : "+v"(wiv[m][q]));
                asm volatile("" : "+v"(whv[m][q]));
            }
        asm volatile("" : "+v"(wit), "+v"(wht));
        const float bs = real ? (b_ih1[wrow] + b_hh1[wrow]) : 0.0f;

        long long budget0 = 100000000LL, budget1 = 100000000LL;
        float c_reg = 0.0f;
        for (int t = 0; t < TT; ++t) {
            if (tid < 64) {                  // wave0: wait layer0 step t done, stage h1[t]
                poll_ge(f0, (unsigned)(t + 1), budget0);
                const float* hp = h1 + (size_t)t * HS;
                float4 v0 = *(const float4*)(hp + lane * 4 + 0);
                float4 v1 = *(const float4*)(hp + lane * 4 + 256);
                float4 v2 = *(const float4*)(hp + lane * 4 + 512);
                float4 v3 = *(const float4*)(hp + lane * 4 + 768);
                float  vt = (lane < 32) ? hp[1024 + lane] : 0.0f;
                *(float4*)&a_lds[lane * 4 + 0]   = v0;
                *(float4*)&a_lds[lane * 4 + 256] = v1;
                *(float4*)&a_lds[lane * 4 + 512] = v2;
                *(float4*)&a_lds[lane * 4 + 768] = v3;
                if (lane < 32) a_lds[1024 + lane] = vt;
            } else if (tid < 128 && t > 0) { // wave1: wait peers step t-1, stage h2[t-1]
                poll_ge(f1, (unsigned)t, budget1);
                const float* hp = h2 + (size_t)(t - 1) * HS;
                float4 v0 = *(const float4*)(hp + lane * 4 + 0);
                float4 v1 = *(const float4*)(hp + lane * 4 + 256);
                float4 v2 = *(const float4*)(hp + lane * 4 + 512);
                float4 v3 = *(const float4*)(hp + lane * 4 + 768);
                float  vt = (lane < 32) ? hp[1024 + lane] : 0.0f;
                *(float4*)&b_lds[lane * 4 + 0]   = v0;
                *(float4*)&b_lds[lane * 4 + 256] = v1;
                *(float4*)&b_lds[lane * 4 + 512] = v2;
                *(float4*)&b_lds[lane * 4 + 768] = v3;
                if (lane < 32) b_lds[1024 + lane] = vt;
            }
            __syncthreads();
            float acc = 0.0f;
#pragma unroll
            for (int m = 0; m < 8; ++m) {
                const float4 ha = *(const float4*)&a_lds[k0 * 4 + m * 128];
                const float4 hb = *(const float4*)&b_lds[k0 * 4 + m * 128];
                acc = fmaf(wiv[m][0], ha.x, acc);
                acc = fmaf(wiv[m][1], ha.y, acc);
                acc = fmaf(wiv[m][2], ha.z, acc);
                acc = fmaf(wiv[m][3], ha.w, acc);
                acc = fmaf(whv[m][0], hb.x, acc);
                acc = fmaf(whv[m][1], hb.y, acc);
                acc = fmaf(whv[m][2], hb.z, acc);
                acc = fmaf(whv[m][3], hb.w, acc);
            }
            acc = fmaf(wit, a_lds[1024 + k0], acc);
            acc = fmaf(wht, b_lds[1024 + k0], acc);
#pragma unroll
            for (int off = 1; off < 32; off <<= 1) acc += __shfl_xor(acc, off);
            if (k0 == 0) gate_lds[row] = acc + bs;
            __syncthreads();
            if (tid < 64) {
                float hv = 0.0f;
                if (tid < 8) {
                    const float gi = gate_lds[tid];
                    const float gf = gate_lds[8 + tid];
                    const float gg = gate_lds[16 + tid];
                    const float go = gate_lds[24 + tid];
                    const float iv = sigmf(gi), fv = sigmf(gf), gv = tanhf(gg), ov = sigmf(go);
                    c_reg = fv * c_reg + iv * gv;
                    hv = ov * tanhf(c_reg);
                }
                const float a = __shfl(hv, (lane & 3) * 2);
                const float b = __shfl(hv, (lane & 3) * 2 + 1);
                if (tid < 4) {
                    float2 f2 = make_float2(a, b);
                    unsigned long long pk;
                    __builtin_memcpy(&pk, &f2, 8);
                    st_u64((unsigned long long*)(h2 + (size_t)t * HS + wg * 8) + tid, pk);
                }
                asm volatile("s_waitcnt vmcnt(0)" ::: "memory");
                if (tid == 0) st_u16((unsigned short*)f1 + wg, (unsigned short)(t + 1));
            }
        }
    }
}

// ---------- final projection: out[t] = lin_w . h2[t] + lin_b ----------
__global__ __launch_bounds__(256) void wn_proj(
    const float* __restrict__ h2,
    const float* __restrict__ lin_w,
    const float* __restrict__ lin_b,
    float* __restrict__ out)
{
    const int lane = threadIdx.x & 63;
    const int wv   = threadIdx.x >> 6;
    const int t    = blockIdx.x * 4 + wv;
    const float* hp = h2 + (size_t)t * HS;
    float acc = 0.0f;
#pragma unroll
    for (int m = 0; m < 4; ++m) {
        const int j = lane * 4 + m * 256;        // covers [0,1024)
        const float4 h4 = *(const float4*)(hp + j);
        const float4 w4 = *(const float4*)(lin_w + j);
        acc += h4.x * w4.x + h4.y * w4.y + h4.z * w4.z + h4.w * w4.w;
    }
    if (lane == 0) {
#pragma unroll
        for (int j = 1024; j < HH; ++j) acc += hp[j] * lin_w[j];
    }
#pragma unroll
    for (int off = 1; off < 64; off <<= 1) acc += __shfl_xor(acc, off);
    if (lane == 0) out[t] = acc + lin_b[0];
}

extern "C" void kernel_launch(void* const* d_in, const int* in_sizes, int n_in,
                              void* d_out, int out_size, void* d_ws, size_t ws_size,
                              hipStream_t stream) {
    const float* x     = (const float*)d_in[0];
    const float* w_ih0 = (const float*)d_in[1];
    const float* w_hh0 = (const float*)d_in[2];
    const float* b_ih0 = (const float*)d_in[3];
    const float* b_hh0 = (const float*)d_in[4];
    const float* w_ih1 = (const float*)d_in[5];
    const float* w_hh1 = (const float*)d_in[6];
    const float* b_ih1 = (const float*)d_in[7];
    const float* b_hh1 = (const float*)d_in[8];
    const float* lin_w = (const float*)d_in[9];
    const float* lin_b = (const float*)d_in[10];
    float* out = (float*)d_out;

    char* ws = (char*)d_ws;
    const size_t SZ = (size_t)TT * HS * sizeof(float);   // 69,206,016 B per h-buffer
    float* h1 = (float*)(ws);
    float* h2 = (float*)(ws + SZ);
    unsigned short* f0 = (unsigned short*)(ws + 2 * SZ);         // 136 ushorts (272 B)
    unsigned short* f1 = (unsigned short*)(ws + 2 * SZ + 512);   // separate cache lines

    wn_init<<<1, 192, 0, stream>>>(f0, f1);
    wn_fused<<<NWGT, 1024, 0, stream>>>(x, w_ih0, w_hh0, b_ih0, b_hh0,
                                        w_ih1, w_hh1, b_ih1, b_hh1, h1, h2,
                                        (unsigned long long*)f0, (unsigned long long*)f1);
    wn_proj<<<TT / 4, 256, 0, stream>>>(h2, lin_w, lin_b, out);
}

// Round 6
// 51237.701 us; speedup vs baseline: 5.9168x; 2.0841x over previous
//
#include <hip/hip_runtime.h>
#include <math.h>

// Problem constants
#define HH    1028        // real hidden size
#define TT    16384       // timesteps
#define UP    1056        // padded units / padded K (= 16*66 = 8*132)
#define HSU   1056        // (val,tag) u64 pairs per ring row (8448 B = 132 lines)
#define HS    1056        // floats per h2 history row
#define NWG0  66          // layer-0 WGs, 16 units each
#define NWG1  132         // layer-1 WGs, 8 units each
#define NWGT  (NWG0 + NWG1)
#define R0    4096        // h1 ring depth (slots)
#define R0M   (R0 - 1)
#define R1M   15          // h2 ring depth 16

// ---------- MALL-coherent primitives (sc1: bypass L1/L2, served at MALL) ----------
__device__ __forceinline__ unsigned long long ld_u64(const unsigned long long* p) {
    return __hip_atomic_load(p, __ATOMIC_RELAXED, __HIP_MEMORY_SCOPE_AGENT);
}
__device__ __forceinline__ void st_u64(unsigned long long* p, unsigned long long v) {
    __hip_atomic_store(p, v, __ATOMIC_RELAXED, __HIP_MEMORY_SCOPE_AGENT);
}
__device__ __forceinline__ unsigned ld_u32(const unsigned* p) {
    return __hip_atomic_load(p, __ATOMIC_RELAXED, __HIP_MEMORY_SCOPE_AGENT);
}
__device__ __forceinline__ void st_u32(unsigned* p, unsigned v) {
    __hip_atomic_store(p, v, __ATOMIC_RELAXED, __HIP_MEMORY_SCOPE_AGENT);
}
__device__ __forceinline__ float sigmf(float x) { return 1.0f / (1.0f + expf(-x)); }

// One staging wave covers 264 (val,tag) pairs at [base, base+264). Polls until
// every pair carries `want` in its tag word; matched values go straight to LDS.
// Retries are exec-masked to the not-yet-arrived pairs only.
__device__ __forceinline__ void stage_poll(const unsigned long long* __restrict__ src,
                                           float* __restrict__ lds, int base, int lane,
                                           unsigned want, long long& budget) {
    const int i0 = base + lane, i1 = i0 + 64, i2 = i0 + 128, i3 = i0 + 192, i4 = i0 + 256;
    bool d0 = false, d1 = false, d2 = false, d3 = false, d4 = (lane >= 8);
    for (;;) {
        if (!d0) { unsigned long long v = ld_u64(src + i0);
                   if ((unsigned)(v >> 32) == want) { lds[i0] = __uint_as_float((unsigned)v); d0 = true; } }
        if (!d1) { unsigned long long v = ld_u64(src + i1);
                   if ((unsigned)(v >> 32) == want) { lds[i1] = __uint_as_float((unsigned)v); d1 = true; } }
        if (!d2) { unsigned long long v = ld_u64(src + i2);
                   if ((unsigned)(v >> 32) == want) { lds[i2] = __uint_as_float((unsigned)v); d2 = true; } }
        if (!d3) { unsigned long long v = ld_u64(src + i3);
                   if ((unsigned)(v >> 32) == want) { lds[i3] = __uint_as_float((unsigned)v); d3 = true; } }
        if (!d4) { unsigned long long v = ld_u64(src + i4);
                   if ((unsigned)(v >> 32) == want) { lds[i4] = __uint_as_float((unsigned)v); d4 = true; } }
        if (__all(d0 & d1 & d2 & d3 & d4)) break;
        if (--budget < 0) break;              // hang safety valve (fails loudly, no hang)
        __builtin_amdgcn_s_sleep(1);
    }
}

// ---------- fused 2-layer LSTM recurrence ----------
__global__ __launch_bounds__(1024, 4) void wn_fused(
    const float* __restrict__ x,
    const float* __restrict__ w_ih0, const float* __restrict__ w_hh0,
    const float* __restrict__ b_ih0, const float* __restrict__ b_hh0,
    const float* __restrict__ w_ih1, const float* __restrict__ w_hh1,
    const float* __restrict__ b_ih1, const float* __restrict__ b_hh1,
    unsigned long long* __restrict__ ring0,   // [R0][HSU] (val,tag) of h1
    unsigned long long* __restrict__ ring1,   // [16][HSU] (val,tag) of h2
    float* __restrict__ h2hist,               // [TT][HS] plain h2 for projection
    unsigned* __restrict__ l1prog)            // L1 WG0 progress (poison-tolerant)
{
    __shared__ float smem[2 * UP + 64];       // L0: h | gates; L1: a | b | gates
    const int tid  = threadIdx.x;
    const int lane = tid & 63;

    if (blockIdx.x < NWG0) {
        // ================= layer 0 : 16 units, 64 rows x 16 lanes =================
        float* h_lds    = smem;
        float* gate_lds = smem + 2 * UP;
        const int wg   = blockIdx.x;
        const int row  = tid >> 4;            // 0..63 = gate*16 + du
        const int k0   = tid & 15;
        const int gate = row >> 4;
        const int du   = row & 15;
        const int u    = wg * 16 + du;
        const bool real = (u < HH);
        const int wrow = gate * HH + (real ? u : 0);

        for (int i = tid; i < UP; i += 1024) h_lds[i] = 0.0f;

        float wv[16][4], wt0 = 0.f, wt1 = 0.f;
#pragma unroll
        for (int m = 0; m < 16; ++m) {
            const int j = k0 * 4 + m * 64;
#pragma unroll
            for (int q = 0; q < 4; ++q)
                wv[m][q] = (real && j + q < HH) ? w_hh0[(size_t)wrow * HH + j + q] : 0.0f;
        }
        {   const int j = 1024 + k0 * 2;
            wt0 = (real && j     < HH) ? w_hh0[(size_t)wrow * HH + j]     : 0.0f;
            wt1 = (real && j + 1 < HH) ? w_hh0[(size_t)wrow * HH + j + 1] : 0.0f; }
#pragma unroll
        for (int m = 0; m < 16; ++m)
#pragma unroll
            for (int q = 0; q < 4; ++q) asm volatile("" : "+v"(wv[m][q]));
        asm volatile("" : "+v"(wt0), "+v"(wt1));

        const float wx = real ? w_ih0[wrow] : 0.0f;
        const float bs = real ? (b_ih0[wrow] + b_hh0[wrow]) : 0.0f;
        __syncthreads();                      // clear visible before first compute/stage

        long long budget = 20000000LL;
        float c_reg = 0.0f;
        for (int t = 0; t < TT; ++t) {
            const float xt = x[t];
            if (t > 0 && tid < 256)           // waves 0-3: poll+stage h1[t-1] (tag t)
                stage_poll(ring0 + (size_t)((t - 1) & R0M) * HSU, h_lds,
                           (tid >> 6) * 264, lane, (unsigned)t, budget);
            __syncthreads();                  // stage visible
            float acc = 0.0f;
#pragma unroll
            for (int m = 0; m < 16; ++m) {
                const float4 hv = *(const float4*)&h_lds[k0 * 4 + m * 64];
                acc = fmaf(wv[m][0], hv.x, acc);
                acc = fmaf(wv[m][1], hv.y, acc);
                acc = fmaf(wv[m][2], hv.z, acc);
                acc = fmaf(wv[m][3], hv.w, acc);
            }
            {   const float2 hv = *(const float2*)&h_lds[1024 + k0 * 2];
                acc = fmaf(wt0, hv.x, acc);
                acc = fmaf(wt1, hv.y, acc); }
#pragma unroll
            for (int off = 1; off < 16; off <<= 1) acc += __shfl_xor(acc, off);
            if (k0 == 0) gate_lds[row] = acc + xt * wx + bs;
            __syncthreads();                  // gates visible; LDS reads done
            // ring backpressure: never lap L1 (checked every 256 steps; poison->wait)
            if (tid == 0 && t > 0 && (t & 255) == 0) {
                for (;;) {
                    unsigned p = ld_u32(l1prog);
                    if ((int)t - (int)p < R0 - 512) break;
                    if (--budget < 0) break;
                    __builtin_amdgcn_s_sleep(32);
                }
            }
            if (tid < 16) {                   // publish: 16 (val,tag) pairs, fire-and-forget
                float hv = 0.0f;
                const float gi = gate_lds[tid];
                const float gf = gate_lds[16 + tid];
                const float gg = gate_lds[32 + tid];
                const float go = gate_lds[48 + tid];
                const float iv = sigmf(gi), fv = sigmf(gf), gv = tanhf(gg), ov = sigmf(go);
                c_reg = fv * c_reg + iv * gv;
                hv = ov * tanhf(c_reg);
                if (wg * 16 + tid >= HH) hv = 0.0f;    // pad units publish 0
                unsigned long long pk = ((unsigned long long)(unsigned)(t + 1) << 32)
                                        | (unsigned long long)__float_as_uint(hv);
                st_u64(ring0 + (size_t)(t & R0M) * HSU + wg * 16 + tid, pk);
            }
        }
    } else {
        // ================= layer 1 : 8 units, 32 rows x 32 lanes =================
        float* a_lds    = smem;               // h1[t]
        float* b_lds    = smem + UP;          // h2[t-1]
        float* gate_lds = smem + 2 * UP;
        const int wg   = blockIdx.x - NWG0;   // 0..131
        const int row  = tid >> 5;            // 0..31 = gate*8 + du
        const int k0   = tid & 31;
        const int gate = row >> 3;
        const int du   = row & 7;
        const int u    = wg * 8 + du;
        const bool real = (u < HH);
        const int wrow = gate * HH + (real ? u : 0);

        for (int i = tid; i < 2 * UP; i += 1024) smem[i] = 0.0f;

        float wiv[8][4], whv[8][4], wit = 0.f, wht = 0.f;
#pragma unroll
        for (int m = 0; m < 8; ++m) {
            const int j = k0 * 4 + m * 128;
#pragma unroll
            for (int q = 0; q < 4; ++q) {
                const bool inb = real && (j + q < HH);
                wiv[m][q] = inb ? w_ih1[(size_t)wrow * HH + j + q] : 0.0f;
                whv[m][q] = inb ? w_hh1[(size_t)wrow * HH + j + q] : 0.0f;
            }
        }
        {   const int j = 1024 + k0;
            wit = (real && j < HH) ? w_ih1[(size_t)wrow * HH + j] : 0.0f;
            wht = (real && j < HH) ? w_hh1[(size_t)wrow * HH + j] : 0.0f; }
#pragma unroll
        for (int m = 0; m < 8; ++m)
#pragma unroll
            for (int q = 0; q < 4; ++q) {
                asm volatile("" : "+v"(wiv[m][q]));
                asm volatile("" : "+v"(whv[m][q]));
            }
        asm volatile("" : "+v"(wit), "+v"(wht));
        const float bs = real ? (b_ih1[wrow] + b_hh1[wrow]) : 0.0f;
        __syncthreads();                      // clear visible before first stage

        long long budget = 20000000LL;
        float c_reg = 0.0f;
        for (int t = 0; t < TT; ++t) {
            if (tid < 256) {                  // waves 0-3: poll+stage h1[t] (tag t+1)
                stage_poll(ring0 + (size_t)(t & R0M) * HSU, a_lds,
                           (tid >> 6) * 264, lane, (unsigned)(t + 1), budget);
            } else if (tid < 512 && t > 0) {  // waves 4-7: poll+stage h2[t-1] (tag t)
                stage_poll(ring1 + (size_t)((t - 1) & R1M) * HSU, b_lds,
                           ((tid >> 6) - 4) * 264, lane, (unsigned)t, budget);
            }
            __syncthreads();
            float acc = 0.0f;
#pragma unroll
            for (int m = 0; m < 8; ++m) {
                const float4 ha = *(const float4*)&a_lds[k0 * 4 + m * 128];
                const float4 hb = *(const float4*)&b_lds[k0 * 4 + m * 128];
                acc = fmaf(wiv[m][0], ha.x, acc);
                acc = fmaf(wiv[m][1], ha.y, acc);
                acc = fmaf(wiv[m][2], ha.z, acc);
                acc = fmaf(wiv[m][3], ha.w, acc);
                acc = fmaf(whv[m][0], hb.x, acc);
                acc = fmaf(whv[m][1], hb.y, acc);
                acc = fmaf(whv[m][2], hb.z, acc);
                acc = fmaf(whv[m][3], hb.w, acc);
            }
            acc = fmaf(wit, a_lds[1024 + k0], acc);
            acc = fmaf(wht, b_lds[1024 + k0], acc);
#pragma unroll
            for (int off = 1; off < 32; off <<= 1) acc += __shfl_xor(acc, off);
            if (k0 == 0) gate_lds[row] = acc + bs;
            __syncthreads();
            if (tid < 8) {                    // publish: 8 pairs + plain-float history
                float hv = 0.0f;
                const float gi = gate_lds[tid];
                const float gf = gate_lds[8 + tid];
                const float gg = gate_lds[16 + tid];
                const float go = gate_lds[24 + tid];
                const float iv = sigmf(gi), fv = sigmf(gf), gv = tanhf(gg), ov = sigmf(go);
                c_reg = fv * c_reg + iv * gv;
                hv = ov * tanhf(c_reg);
                if (wg * 8 + tid >= HH) hv = 0.0f;
                unsigned long long pk = ((unsigned long long)(unsigned)(t + 1) << 32)
                                        | (unsigned long long)__float_as_uint(hv);
                st_u64(ring1 + (size_t)(t & R1M) * HSU + wg * 8 + tid, pk);
                h2hist[(size_t)t * HS + wg * 8 + tid] = hv;   // normal store, kernel-end flush
            }
            if (tid == 0 && wg == 0 && (t & 255) == 255)
                st_u32(l1prog, (unsigned)(t + 1));            // backpressure progress
        }
    }
}

// ---------- final projection: out[t] = lin_w . h2[t] + lin_b ----------
__global__ __launch_bounds__(256) void wn_proj(
    const float* __restrict__ h2,
    const float* __restrict__ lin_w,
    const float* __restrict__ lin_b,
    float* __restrict__ out)
{
    const int lane = threadIdx.x & 63;
    const int wv   = threadIdx.x >> 6;
    const int t    = blockIdx.x * 4 + wv;
    const float* hp = h2 + (size_t)t * HS;
    float acc = 0.0f;
#pragma unroll
    for (int m = 0; m < 4; ++m) {
        const int j = lane * 4 + m * 256;        // covers [0,1024)
        const float4 h4 = *(const float4*)(hp + j);
        const float4 w4 = *(const float4*)(lin_w + j);
        acc += h4.x * w4.x + h4.y * w4.y + h4.z * w4.z + h4.w * w4.w;
    }
    if (lane == 0) {
#pragma unroll
        for (int j = 1024; j < HH; ++j) acc += hp[j] * lin_w[j];
    }
#pragma unroll
    for (int off = 1; off < 64; off <<= 1) acc += __shfl_xor(acc, off);
    if (lane == 0) out[t] = acc + lin_b[0];
}

extern "C" void kernel_launch(void* const* d_in, const int* in_sizes, int n_in,
                              void* d_out, int out_size, void* d_ws, size_t ws_size,
                              hipStream_t stream) {
    const float* x     = (const float*)d_in[0];
    const float* w_ih0 = (const float*)d_in[1];
    const float* w_hh0 = (const float*)d_in[2];
    const float* b_ih0 = (const float*)d_in[3];
    const float* b_hh0 = (const float*)d_in[4];
    const float* w_ih1 = (const float*)d_in[5];
    const float* w_hh1 = (const float*)d_in[6];
    const float* b_ih1 = (const float*)d_in[7];
    const float* b_hh1 = (const float*)d_in[8];
    const float* lin_w = (const float*)d_in[9];
    const float* lin_b = (const float*)d_in[10];
    float* out = (float*)d_out;

    char* ws = (char*)d_ws;
    const size_t R0B = (size_t)R0 * HSU * 8;        // 34,603,008
    const size_t R1B = (size_t)16 * HSU * 8;        //    135,168
    const size_t H2B = (size_t)TT * HS * 4;         // 69,206,016
    unsigned long long* ring0 = (unsigned long long*)(ws);
    unsigned long long* ring1 = (unsigned long long*)(ws + R0B);
    float* h2hist = (float*)(ws + R0B + R1B);
    unsigned* l1prog = (unsigned*)(ws + R0B + R1B + H2B);
    // No init kernel: 0xAA poison never matches any tag (1..16384), and the
    // poisoned l1prog reads as negative -> L0 throttles until L1 publishes.

    wn_fused<<<NWGT, 1024, 0, stream>>>(x, w_ih0, w_hh0, b_ih0, b_hh0,
                                        w_ih1, w_hh1, b_ih1, b_hh1,
                                        ring0, ring1, h2hist, l1prog);
    wn_proj<<<TT / 4, 256, 0, stream>>>(h2hist, lin_w, lin_b, out);
}